// Round 9
// baseline (465.189 us; speedup 1.0000x reference)
//
#include <hip/hip_runtime.h>

typedef unsigned short ushort_t;
typedef __attribute__((ext_vector_type(8))) short short8;
typedef __attribute__((ext_vector_type(4))) float floatx4;

#define B_ 8
#define S_ 4096
#define E_ 1024
#define SD_ 8
#define M_TOTAL (B_ * S_)   /* 32768 rows */
#define NC 1032             /* E+SD real columns of W_in */
#define KX 1152             /* unified K: 1024 x-cols + 16 state/gate + 112 pad */

__device__ __forceinline__ ushort_t f2bf(float f) {
    union { float f; unsigned u; } v; v.f = f;
    unsigned u = v.u;
    unsigned r = (u + 0x7fffu + ((u >> 16) & 1u)) >> 16;  // RNE
    return (ushort_t)r;
}
__device__ __forceinline__ float bf2f(ushort_t h) {
    union { unsigned u; float f; } v; v.u = ((unsigned)h) << 16;
    return v.f;
}

// Async global->LDS, 16B per lane. LDS dest is wave-uniform base + lane*16.
__device__ __forceinline__ void gload16(char* lds_uniform, const ushort_t* g) {
    __builtin_amdgcn_global_load_lds(
        (const __attribute__((address_space(1))) void*)g,
        (__attribute__((address_space(3))) void*)lds_uniform, 16, 0, 0);
}

// ---------------- prep_ew2 (R8-proven merge pattern, +1 verbatim-style segment) ----
// blocks [0,1024):      Winb = bf16(W_in[:, :1024])
// blocks [1024,5120):   WoutTa[n][j] = bf16(W_out[j][n])
// blocks [5120,5632):   WbigTX[n][1024+c] = W_out[1024+c][n] (c<8) else 0
__global__ __launch_bounds__(256) void prep_ew2(
    const float* __restrict__ W_in, const float* __restrict__ W_out,
    ushort_t* __restrict__ Winb, ushort_t* __restrict__ WoutTa,
    ushort_t* __restrict__ WbigTX)
{
    const int bid = blockIdx.x, tid = threadIdx.x;
    if (bid < 1024) {
        int i = bid * 256 + tid;
        int k = i >> 8, j0 = (i & 255) * 4;
        float4 v = *(const float4*)(W_in + (size_t)k * NC + j0);
        ushort4 o;
        o.x = f2bf(v.x); o.y = f2bf(v.y); o.z = f2bf(v.z); o.w = f2bf(v.w);
        *(ushort4*)(Winb + (size_t)k * E_ + j0) = o;
    } else if (bid < 5120) {
        int idx = (bid - 1024) * 256 + tid;
        int n = idx >> 10, j = idx & 1023;
        WoutTa[idx] = f2bf(W_out[(size_t)j * E_ + n]);
    } else {
        int idx = (bid - 5120) * 256 + tid;    // 0..131071
        int n = idx >> 7, c = idx & 127;
        WbigTX[(size_t)n * KX + 1024 + c] =
            (c < 8) ? f2bf(W_out[(size_t)(1024 + c) * E_ + n]) : (ushort_t)0;
    }
}

// ---------------- remaining prep (R8-proven, byte-identical) ----------------
__global__ void wcomb_kernel(const float* __restrict__ W_in, const float* __restrict__ Wg,
                             float* __restrict__ Wc) {
    const int k = blockIdx.x;
    const int lane = threadIdx.x;
    float acc[8] = {0.f,0.f,0.f,0.f,0.f,0.f,0.f,0.f};
    for (int c = lane; c < NC; c += 64) {
        float w = W_in[(size_t)k * NC + c];
#pragma unroll
        for (int d = 0; d < 8; d++) acc[d] += w * Wg[(size_t)c * 8 + d];
    }
#pragma unroll
    for (int d = 0; d < 8; d++) {
#pragma unroll
        for (int off = 32; off >= 1; off >>= 1) acc[d] += __shfl_xor(acc[d], off);
    }
    if (lane == 0) {
#pragma unroll
        for (int d = 0; d < 8; d++) Wc[k * 8 + d] = acc[d];
    }
}

__global__ void prep_small(const float* __restrict__ W_in, const float* __restrict__ Wc,
                           const float* __restrict__ W_out, const float* __restrict__ b_in,
                           const float* __restrict__ Wg, const float* __restrict__ bg,
                           ushort_t* __restrict__ BT16, ushort_t* __restrict__ WoutT2,
                           float* __restrict__ bias16) {
    int idx = blockIdx.x * 256 + threadIdx.x;
    if (idx < 32768) {
        int n = idx >> 10, k = idx & 1023;
        float v;
        if (n < 8)        v = W_in[(size_t)k * NC + 1024 + n];
        else if (n < 16)  v = Wc[k * 8 + (n - 8)];
        else              v = 0.f;
        BT16[idx] = f2bf(v);
    } else {
        int i2 = idx - 32768;
        int n = i2 >> 5, k2 = i2 & 31;
        float v = (k2 < 8) ? W_out[(size_t)(1024 + k2) * E_ + n] : 0.f;
        WoutT2[i2] = f2bf(v);
    }
    if (idx < 32) {
        float s;
        if (idx < 8) s = b_in[1024 + idx];
        else if (idx < 16) {
            int d = idx - 8;
            s = bg[d];
            for (int j = 0; j < NC; j++) s += b_in[j] * Wg[(size_t)j * 8 + d];
        } else s = 0.f;
        bias16[idx] = s;
    }
}

__global__ void bias2_kernel(const float* __restrict__ b_in, const float* __restrict__ W_out,
                             const float* __restrict__ b_out, float* __restrict__ bias2) {
    int n = blockIdx.x * 64 + threadIdx.x;
    float acc = b_out[n];
    for (int j = 0; j < E_; j++) acc += b_in[j] * W_out[(size_t)j * E_ + n];
    bias2[n] = acc;
}

// ---------------- m97-style GEMM (R8-proven) — used only for the 1024^3 weight GEMM --
template <bool OUT_BF16>
__global__ __launch_bounds__(256, 2) void gemm_bt(
    const ushort_t* __restrict__ A, const ushort_t* __restrict__ BT,
    void* __restrict__ Cout, const float* __restrict__ bias,
    int K, int lda, int ldb, int ldc)
{
    __shared__ __align__(16) ushort_t sA[128 * 32];
    __shared__ __align__(16) ushort_t sB[128 * 32];
    const int tid = threadIdx.x;
    const int wave = tid >> 6;
    const int lane = tid & 63;

    const int gx = gridDim.x;
    int flat = blockIdx.y * gx + blockIdx.x;
    const int band_size = 8 * gx;
    int band = flat / band_size;
    int r = flat - band * band_size;
    const int m0 = (band * 8 + (r & 7)) * 128;
    const int n0 = (r >> 3) * 128;

    const int wm = wave >> 1, wn = wave & 1;
    const int fr = lane & 15, fq = lane >> 4;
    const int sr = lane >> 2;
    const int sc = (lane & 3) * 8;

    floatx4 acc[4][4];
#pragma unroll
    for (int i = 0; i < 4; i++)
#pragma unroll
        for (int j = 0; j < 4; j++) acc[i][j] = (floatx4)0.f;

    const ushort_t* gA = A + (size_t)(m0 + wave * 32 + sr) * lda + sc;
    const ushort_t* gB = BT + (size_t)(n0 + wave * 32 + sr) * ldb + sc;

    for (int k0 = 0; k0 < K; k0 += 32) {
        __syncthreads();
        gload16((char*)&sA[(wave * 32 + 0) * 32], gA + k0);
        gload16((char*)&sA[(wave * 32 + 16) * 32], gA + (size_t)16 * lda + k0);
        gload16((char*)&sB[(wave * 32 + 0) * 32], gB + k0);
        gload16((char*)&sB[(wave * 32 + 16) * 32], gB + (size_t)16 * ldb + k0);
        __syncthreads();

        short8 a[4], b[4];
#pragma unroll
        for (int i = 0; i < 4; i++)
            a[i] = *(const short8*)&sA[(wm * 64 + i * 16 + fr) * 32 + fq * 8];
#pragma unroll
        for (int j = 0; j < 4; j++)
            b[j] = *(const short8*)&sB[(wn * 64 + j * 16 + fr) * 32 + fq * 8];
#pragma unroll
        for (int i = 0; i < 4; i++)
#pragma unroll
            for (int j = 0; j < 4; j++)
                acc[i][j] = __builtin_amdgcn_mfma_f32_16x16x32_bf16(a[i], b[j], acc[i][j], 0, 0, 0);
    }

#pragma unroll
    for (int i = 0; i < 4; i++) {
        int row = m0 + wm * 64 + i * 16 + fq * 4;
#pragma unroll
        for (int j = 0; j < 4; j++) {
            int col = n0 + wn * 64 + j * 16 + fr;
            float bv = bias ? bias[col] : 0.f;
#pragma unroll
            for (int r2 = 0; r2 < 4; r2++) {
                float v = acc[i][j][r2] + bv;
                if (OUT_BF16)
                    ((ushort_t*)Cout)[(size_t)(row + r2) * ldc + col] = f2bf(v);
                else
                    ((float*)Cout)[(size_t)(row + r2) * ldc + col] = v;
            }
        }
    }
}

// ---------------- gemm256: 256x256 tile, BK=64, 8 waves, counted vmcnt, swizzled LDS --
// out[32768][1024] = XC[32768][1152] @ WbigTX[1024][1152]^T + bias.
// LDS ring: sA[2][256][64], sB[2][256][64] bf16 = 128 KiB (dynamic).
// Swizzle (T2, st_16x32): byte p stores logical q = p ^ (((p>>9)&1)<<5) — involution;
// staging pre-swizzles the GLOBAL source (linear LDS dest required by global_load_lds),
// reads apply the same XOR. Schedule per K-tile t: [stage(t+1,Ah0); vmcnt(2); barrier;
// b-frags; quad0; stage Ah1; quad1; stage Bh0; quad2; stage Bh1; quad3; barrier].
// vmcnt(2) = own 8 loads for tile t complete, own just-issued prefetch in flight (T4).
#define NT 18   /* 1152 / 64 */
__global__ __launch_bounds__(512, 2) void gemm256(
    const ushort_t* __restrict__ A, const ushort_t* __restrict__ BT,
    float* __restrict__ out, const float* __restrict__ bias)
{
    extern __shared__ char smem[];     // 131072 B
    const int tid = threadIdx.x;
    const int w = tid >> 6, lane = tid & 63;
    const int wm = w >> 2, wn = w & 3;           // 2x4 waves -> 128x64 output each
    const int fr = lane & 15, fq = lane >> 4;

    // XCD swizzle: 512 wgs, 8 XCDs -> xcd gets 64 consecutive wgs (16 mtiles x 4 ntiles)
    int flat = blockIdx.x;
    int wg = (flat & 7) * 64 + (flat >> 3);
    const int m0 = (wg >> 2) * 256;
    const int n0 = (wg & 3) * 256;

    // ---- staging geometry (2 loads/thread per 16KB half-tile) ----
    const int w2 = w * 2;
    const int sr0 = (w2 + 0) * 8 + (lane >> 3);  // row in half, load 0
    const int sr1 = (w2 + 1) * 8 + (lane >> 3);  // row in half, load 1
    const int scole = (((lane & 7) * 16) ^ ((lane & 32) ? 32 : 0)) >> 1;  // pre-swizzled col elem
    const size_t gA0 = (size_t)(m0 + sr0) * KX + scole;
    const size_t gA1 = (size_t)(m0 + sr1) * KX + scole;
    const size_t gB0 = (size_t)(n0 + sr0) * KX + scole;
    const size_t gB1 = (size_t)(n0 + sr1) * KX + scole;
    const int dstw = w2 * 1024;                  // wave-uniform byte base within half

    // ---- ds-read geometry ----
    const int axor = ((fr >> 2) & 1) << 5;
    const int acol0 = (fq * 16) ^ axor;          // kk=0
    const int acol1 = (64 + fq * 16) ^ axor;     // kk=1
    const int aRd = wm * 16384 + fr * 128;                       // + buf*32768 + i*2048 + acol
    const int bRd = 65536 + (wn >> 1) * 16384 + ((wn & 1) * 64 + fr) * 128;  // + buf*32768 + j*2048 + acol

    floatx4 acc[8][4];
#pragma unroll
    for (int i = 0; i < 8; i++)
#pragma unroll
        for (int j = 0; j < 4; j++) acc[i][j] = (floatx4)0.f;

#define STAGE_A(buf, t, h)                                                   \
    do {                                                                     \
        char* d = smem + (buf) * 32768 + (h) * 16384 + dstw;                 \
        gload16(d,        A + gA0 + (size_t)(h) * 128 * KX + (t) * 64);      \
        gload16(d + 1024, A + gA1 + (size_t)(h) * 128 * KX + (t) * 64);     \
    } while (0)
#define STAGE_B(buf, t, h)                                                   \
    do {                                                                     \
        char* d = smem + 65536 + (buf) * 32768 + (h) * 16384 + dstw;         \
        gload16(d,        BT + gB0 + (size_t)(h) * 128 * KX + (t) * 64);     \
        gload16(d + 1024, BT + gB1 + (size_t)(h) * 128 * KX + (t) * 64);    \
    } while (0)

    // prologue: stage tile 0 into buf 0 (8 loads)
    STAGE_A(0, 0, 0); STAGE_A(0, 0, 1);
    STAGE_B(0, 0, 0); STAGE_B(0, 0, 1);

#pragma unroll 1
    for (int t = 0; t < NT; t++) {
        const int bufR = (t & 1) * 32768;
        const int bufW = ((t + 1) & 1) * 32768;
        const bool more = (t + 1 < NT);

        // ---- tile boundary: counted vmcnt + barrier ----
        if (more) {
            STAGE_A(bufW / 32768, t + 1, 0);
            __builtin_amdgcn_sched_barrier(0);
            asm volatile("s_waitcnt vmcnt(2)" ::: "memory");
        } else {
            __builtin_amdgcn_sched_barrier(0);
            asm volatile("s_waitcnt vmcnt(0)" ::: "memory");
        }
        __builtin_amdgcn_sched_barrier(0);
        __builtin_amdgcn_s_barrier();            // tile t fully visible in LDS
        __builtin_amdgcn_sched_barrier(0);

        // ---- b-fragments for the whole tile (8 x ds_read_b128) ----
        short8 b[4][2];
#pragma unroll
        for (int j = 0; j < 4; j++) {
            b[j][0] = *(const short8*)(smem + bufR + bRd + j * 2048 + acol0);
            b[j][1] = *(const short8*)(smem + bufR + bRd + j * 2048 + acol1);
        }

        // ---- 4 quadrants (i-pairs), staging interleaved ----
#pragma unroll
        for (int q = 0; q < 4; q++) {
            short8 a[2][2];
#pragma unroll
            for (int i2 = 0; i2 < 2; i2++) {
                int i = q * 2 + i2;
                a[i2][0] = *(const short8*)(smem + bufR + aRd + i * 2048 + acol0);
                a[i2][1] = *(const short8*)(smem + bufR + aRd + i * 2048 + acol1);
            }
            __builtin_amdgcn_s_setprio(1);
#pragma unroll
            for (int i2 = 0; i2 < 2; i2++)
#pragma unroll
                for (int j = 0; j < 4; j++)
#pragma unroll
                    for (int kk = 0; kk < 2; kk++)
                        acc[q * 2 + i2][j] = __builtin_amdgcn_mfma_f32_16x16x32_bf16(
                            a[i2][kk], b[j][kk], acc[q * 2 + i2][j], 0, 0, 0);
            __builtin_amdgcn_s_setprio(0);
            if (more) {
                if (q == 0) STAGE_A(bufW / 32768, t + 1, 1);
                else if (q == 1) STAGE_B(bufW / 32768, t + 1, 0);
                else if (q == 2) STAGE_B(bufW / 32768, t + 1, 1);
            }
        }

        __builtin_amdgcn_s_barrier();            // reads of buf[t] done before its restage
        __builtin_amdgcn_sched_barrier(0);
    }
#undef STAGE_A
#undef STAGE_B

    // ---- epilogue: C/D layout col=lane&15, row=(lane>>4)*4+reg ----
    float bv[4];
#pragma unroll
    for (int j = 0; j < 4; j++) bv[j] = bias[n0 + wn * 64 + j * 16 + fr];
#pragma unroll
    for (int i = 0; i < 8; i++) {
        int row = m0 + wm * 128 + i * 16 + fq * 4;
#pragma unroll
        for (int j = 0; j < 4; j++) {
            int col = n0 + wn * 64 + j * 16 + fr;
#pragma unroll
            for (int r2 = 0; r2 < 4; r2++)
                out[(size_t)(row + r2) * E_ + col] = acc[i][j][r2] + bv[j];
        }
    }
}

// ---------------- fused cvt + skinny GEMM1 (R8-proven; XC stride + zero-pad) --------
__global__ __launch_bounds__(256) void skinny16_cvt(
    const float* __restrict__ X,        // x [32768][1024] fp32
    const ushort_t* __restrict__ BT,    // BT16 [32][1024] (rows 16..31 zero)
    const float* __restrict__ bias,     // [32]
    ushort_t* __restrict__ XC)          // out: [32768][1152] = [bf16(x)|16 comb|112 zeros]
{
    const int tid = threadIdx.x, wave = tid >> 6, lane = tid & 63;
    const int m0 = blockIdx.x * 16;
    const int fr = lane & 15, fq = lane >> 4;
    const int k0w = wave * 256;

    floatx4 acc = (floatx4)0.f;
    const float*    px  = X  + (size_t)(m0 + fr) * E_ + k0w + fq * 8;
    ushort_t*       pxb = XC + (size_t)(m0 + fr) * KX + k0w + fq * 8;
    const ushort_t* pb  = BT + (size_t)fr * E_ + k0w + fq * 8;
#pragma unroll
    for (int kk = 0; kk < 256; kk += 32) {
        float4 v0 = *(const float4*)(px + kk);
        float4 v1 = *(const float4*)(px + kk + 4);
        short8 a;
        a[0] = (short)f2bf(v0.x); a[1] = (short)f2bf(v0.y);
        a[2] = (short)f2bf(v0.z); a[3] = (short)f2bf(v0.w);
        a[4] = (short)f2bf(v1.x); a[5] = (short)f2bf(v1.y);
        a[6] = (short)f2bf(v1.z); a[7] = (short)f2bf(v1.w);
        *(short8*)(pxb + kk) = a;
        short8 b0 = *(const short8*)(pb + kk);
        acc = __builtin_amdgcn_mfma_f32_16x16x32_bf16(a, b0, acc, 0, 0, 0);
    }

    __shared__ float red[4][16][16];
#pragma unroll
    for (int r = 0; r < 4; r++) red[wave][fq * 4 + r][fr] = acc[r];
    __syncthreads();
    const int row = tid >> 4, col = tid & 15;
    float v = red[0][row][col] + red[1][row][col] + red[2][row][col] + red[3][row][col]
            + bias[col];
    ushort_t* xr = XC + (size_t)(m0 + row) * KX;
    xr[1024 + col] = f2bf(v);
#pragma unroll
    for (int z = 0; z < 7; z++) xr[1040 + col + 16 * z] = (ushort_t)0;  // zero cols 1040..1151
}

// ---------------- fused scan (R8-proven; XC stride) ----------------
__global__ __launch_bounds__(256) void scan_fused(
    ushort_t* __restrict__ XC, float* __restrict__ final_state)
{
    const int b = blockIdx.x >> 3, d = blockIdx.x & 7;
    const int t = threadIdx.x;
    __shared__ float sA[256], sB[256];
    const size_t base = (size_t)b * S_ * KX;
    const int s0 = t * 16;

    float A = 1.f, Bv = 0.f;
    for (int s = s0; s < s0 + 16; s++) {
        size_t m = base + (size_t)s * KX;
        float z = bf2f(XC[m + 1032 + d]);
        float g = 1.f / (1.f + __expf(-z));
        float si = bf2f(XC[m + 1024 + d]);
        Bv = g * Bv + (1.f - g) * si;
        A *= g;
    }
    sA[t] = A; sB[t] = Bv;
    __syncthreads();

    float rA = A, rB = Bv;
    for (int off = 1; off < 256; off <<= 1) {
        float a = 1.f, b_ = 0.f;
        if (t >= off) { a = sA[t - off]; b_ = sB[t - off]; }
        __syncthreads();
        if (t >= off) {
            float nA = a * rA;
            float nB = rA * b_ + rB;
            rA = nA; rB = nB;
        }
        sA[t] = rA; sB[t] = rB;
        __syncthreads();
    }

    float state = (t == 0) ? 0.f : sB[t - 1];
    for (int s = s0; s < s0 + 16; s++) {
        size_t m = base + (size_t)s * KX;
        float z = bf2f(XC[m + 1032 + d]);
        float g = 1.f / (1.f + __expf(-z));
        float si = bf2f(XC[m + 1024 + d]);
        state = g * state + (1.f - g) * si;
        XC[m + 1024 + d] = f2bf(state);
    }
    if (t == 255) final_state[b * 8 + d] = state;
}

extern "C" void kernel_launch(void* const* d_in, const int* in_sizes, int n_in,
                              void* d_out, int out_size, void* d_ws, size_t ws_size,
                              hipStream_t stream)
{
    (void)in_sizes; (void)n_in; (void)out_size; (void)ws_size;
    const float* x     = (const float*)d_in[0];
    const float* W_in  = (const float*)d_in[1];
    const float* b_in  = (const float*)d_in[2];
    const float* W_g   = (const float*)d_in[3];
    const float* b_g   = (const float*)d_in[4];
    const float* W_out = (const float*)d_in[5];
    const float* b_out = (const float*)d_in[6];

    // workspace (~78.0 MB, under the 80.2 MB proven in R0).
    // Winb/WoutTa alias XC's head: dead after the wbig GEMM, before skinny overwrites.
    ushort_t* XC     = (ushort_t*)d_ws;                      // 32768*1152 bf16 = 75.5 MB
    ushort_t* Winb   = XC;                                   // 1024*1024 bf16 (aliased)
    ushort_t* WoutTa = XC + (size_t)E_ * E_;                 // 1024*1024 bf16 (aliased)
    ushort_t* WbigTX = XC + (size_t)M_TOTAL * KX;            // 1024*1152 bf16 = 2.36 MB
    ushort_t* WoutT2 = WbigTX + (size_t)E_ * KX;             // 1024*32 bf16 (legacy)
    ushort_t* BT16   = WoutT2 + (size_t)E_ * 32;             // 32*1024 bf16
    float*    Wc     = (float*)(BT16 + (size_t)32 * E_);     // 1024*8 fp32
    float*    bias16 = Wc + 1024 * 8;                        // 32
    float*    bias2v = bias16 + 32;                          // 1024

    float* outp = (float*)d_out;
    float* fs = outp + (size_t)M_TOTAL * E_;  // final_state at element 33554432

    // 1) elementwise weight prep (incl. WbigTX pad cols)
    prep_ew2<<<5632, 256, 0, stream>>>(W_in, W_out, Winb, WoutTa, WbigTX);
    // 2-4) R8-proven prep chain
    wcomb_kernel<<<E_, 64, 0, stream>>>(W_in, W_g, Wc);
    prep_small<<<256, 256, 0, stream>>>(W_in, Wc, W_out, b_in, W_g, b_g, BT16, WoutT2, bias16);
    bias2_kernel<<<E_ / 64, 64, 0, stream>>>(b_in, W_out, b_out, bias2v);

    // 5) WbigTX[:, :1024] = (W_in[:,:1024] @ W_out[:1024,:])^T   (ldc = 1152)
    gemm_bt<true><<<dim3(E_ / 128, E_ / 128), 256, 0, stream>>>(
        WoutTa, Winb, WbigTX, nullptr, E_, E_, E_, KX);

    // 6) fused cvt+skinny: XC = [bf16(x) | x@BT16^T + bias16 | zeros]
    skinny16_cvt<<<M_TOTAL / 16, 256, 0, stream>>>(x, BT16, bias16, XC);

    // 7) fused scan (overwrites state_in cols with states)
    scan_fused<<<64, 256, 0, stream>>>(XC, fs);

    // 8) gemm256: out = XC @ WbigTX^T + bias2  (K=1152, 128 KiB dynamic LDS)
    gemm256<<<512, 512, 131072, stream>>>(XC, WbigTX, outp, bias2v);
}

// Round 10
// 449.543 us; speedup vs baseline: 1.0348x; 1.0348x over previous
//
#include <hip/hip_runtime.h>

typedef unsigned short ushort_t;
typedef __attribute__((ext_vector_type(8))) short short8;
typedef __attribute__((ext_vector_type(4))) float floatx4;

#define B_ 8
#define S_ 4096
#define E_ 1024
#define SD_ 8
#define M_TOTAL (B_ * S_)   /* 32768 rows */
#define NC 1032             /* E+SD real columns of W_in */
#define KX 1088             /* unified K: 1024 x-cols + 16 state/gate + 48 pad (17 tiles) */

__device__ __forceinline__ ushort_t f2bf(float f) {
    union { float f; unsigned u; } v; v.f = f;
    unsigned u = v.u;
    unsigned r = (u + 0x7fffu + ((u >> 16) & 1u)) >> 16;  // RNE
    return (ushort_t)r;
}
__device__ __forceinline__ float bf2f(ushort_t h) {
    union { unsigned u; float f; } v; v.u = ((unsigned)h) << 16;
    return v.f;
}

// Async global->LDS, 16B per lane. LDS dest is wave-uniform base + lane*16.
__device__ __forceinline__ void gload16(char* lds_uniform, const ushort_t* g) {
    __builtin_amdgcn_global_load_lds(
        (const __attribute__((address_space(1))) void*)g,
        (__attribute__((address_space(3))) void*)lds_uniform, 16, 0, 0);
}

// ---------------- prep_ew2 (R8-proven merge pattern) ----------------
// blocks [0,1024):      Winb = bf16(W_in[:, :1024])
// blocks [1024,5120):   WoutTa[n][j] = bf16(W_out[j][n])
// blocks [5120,5376):   WbigTX[n][1024+c] = W_out[1024+c][n] (c<8) else 0   (c<64)
__global__ __launch_bounds__(256) void prep_ew2(
    const float* __restrict__ W_in, const float* __restrict__ W_out,
    ushort_t* __restrict__ Winb, ushort_t* __restrict__ WoutTa,
    ushort_t* __restrict__ WbigTX)
{
    const int bid = blockIdx.x, tid = threadIdx.x;
    if (bid < 1024) {
        int i = bid * 256 + tid;
        int k = i >> 8, j0 = (i & 255) * 4;
        float4 v = *(const float4*)(W_in + (size_t)k * NC + j0);
        ushort4 o;
        o.x = f2bf(v.x); o.y = f2bf(v.y); o.z = f2bf(v.z); o.w = f2bf(v.w);
        *(ushort4*)(Winb + (size_t)k * E_ + j0) = o;
    } else if (bid < 5120) {
        int idx = (bid - 1024) * 256 + tid;
        int n = idx >> 10, j = idx & 1023;
        WoutTa[idx] = f2bf(W_out[(size_t)j * E_ + n]);
    } else {
        int idx = (bid - 5120) * 256 + tid;    // 0..65535
        int n = idx >> 6, c = idx & 63;
        WbigTX[(size_t)n * KX + 1024 + c] =
            (c < 8) ? f2bf(W_out[(size_t)(1024 + c) * E_ + n]) : (ushort_t)0;
    }
}

// ---------------- remaining prep (R8-proven, byte-identical) ----------------
__global__ void wcomb_kernel(const float* __restrict__ W_in, const float* __restrict__ Wg,
                             float* __restrict__ Wc) {
    const int k = blockIdx.x;
    const int lane = threadIdx.x;
    float acc[8] = {0.f,0.f,0.f,0.f,0.f,0.f,0.f,0.f};
    for (int c = lane; c < NC; c += 64) {
        float w = W_in[(size_t)k * NC + c];
#pragma unroll
        for (int d = 0; d < 8; d++) acc[d] += w * Wg[(size_t)c * 8 + d];
    }
#pragma unroll
    for (int d = 0; d < 8; d++) {
#pragma unroll
        for (int off = 32; off >= 1; off >>= 1) acc[d] += __shfl_xor(acc[d], off);
    }
    if (lane == 0) {
#pragma unroll
        for (int d = 0; d < 8; d++) Wc[k * 8 + d] = acc[d];
    }
}

__global__ void prep_small(const float* __restrict__ W_in, const float* __restrict__ Wc,
                           const float* __restrict__ W_out, const float* __restrict__ b_in,
                           const float* __restrict__ Wg, const float* __restrict__ bg,
                           ushort_t* __restrict__ BT16, ushort_t* __restrict__ WoutT2,
                           float* __restrict__ bias16) {
    int idx = blockIdx.x * 256 + threadIdx.x;
    if (idx < 32768) {
        int n = idx >> 10, k = idx & 1023;
        float v;
        if (n < 8)        v = W_in[(size_t)k * NC + 1024 + n];
        else if (n < 16)  v = Wc[k * 8 + (n - 8)];
        else              v = 0.f;
        BT16[idx] = f2bf(v);
    } else {
        int i2 = idx - 32768;
        int n = i2 >> 5, k2 = i2 & 31;
        float v = (k2 < 8) ? W_out[(size_t)(1024 + k2) * E_ + n] : 0.f;
        WoutT2[i2] = f2bf(v);
    }
    if (idx < 32) {
        float s;
        if (idx < 8) s = b_in[1024 + idx];
        else if (idx < 16) {
            int d = idx - 8;
            s = bg[d];
            for (int j = 0; j < NC; j++) s += b_in[j] * Wg[(size_t)j * 8 + d];
        } else s = 0.f;
        bias16[idx] = s;
    }
}

__global__ void bias2_kernel(const float* __restrict__ b_in, const float* __restrict__ W_out,
                             const float* __restrict__ b_out, float* __restrict__ bias2) {
    int n = blockIdx.x * 64 + threadIdx.x;
    float acc = b_out[n];
    for (int j = 0; j < E_; j++) acc += b_in[j] * W_out[(size_t)j * E_ + n];
    bias2[n] = acc;
}

// ---------------- m97-style GEMM (R8-proven) — only for the 1024^3 weight GEMM --
template <bool OUT_BF16>
__global__ __launch_bounds__(256, 2) void gemm_bt(
    const ushort_t* __restrict__ A, const ushort_t* __restrict__ BT,
    void* __restrict__ Cout, const float* __restrict__ bias,
    int K, int lda, int ldb, int ldc)
{
    __shared__ __align__(16) ushort_t sA[128 * 32];
    __shared__ __align__(16) ushort_t sB[128 * 32];
    const int tid = threadIdx.x;
    const int wave = tid >> 6;
    const int lane = tid & 63;

    const int gx = gridDim.x;
    int flat = blockIdx.y * gx + blockIdx.x;
    const int band_size = 8 * gx;
    int band = flat / band_size;
    int r = flat - band * band_size;
    const int m0 = (band * 8 + (r & 7)) * 128;
    const int n0 = (r >> 3) * 128;

    const int wm = wave >> 1, wn = wave & 1;
    const int fr = lane & 15, fq = lane >> 4;
    const int sr = lane >> 2;
    const int sc = (lane & 3) * 8;

    floatx4 acc[4][4];
#pragma unroll
    for (int i = 0; i < 4; i++)
#pragma unroll
        for (int j = 0; j < 4; j++) acc[i][j] = (floatx4)0.f;

    const ushort_t* gA = A + (size_t)(m0 + wave * 32 + sr) * lda + sc;
    const ushort_t* gB = BT + (size_t)(n0 + wave * 32 + sr) * ldb + sc;

    for (int k0 = 0; k0 < K; k0 += 32) {
        __syncthreads();
        gload16((char*)&sA[(wave * 32 + 0) * 32], gA + k0);
        gload16((char*)&sA[(wave * 32 + 16) * 32], gA + (size_t)16 * lda + k0);
        gload16((char*)&sB[(wave * 32 + 0) * 32], gB + k0);
        gload16((char*)&sB[(wave * 32 + 16) * 32], gB + (size_t)16 * ldb + k0);
        __syncthreads();

        short8 a[4], b[4];
#pragma unroll
        for (int i = 0; i < 4; i++)
            a[i] = *(const short8*)&sA[(wm * 64 + i * 16 + fr) * 32 + fq * 8];
#pragma unroll
        for (int j = 0; j < 4; j++)
            b[j] = *(const short8*)&sB[(wn * 64 + j * 16 + fr) * 32 + fq * 8];
#pragma unroll
        for (int i = 0; i < 4; i++)
#pragma unroll
            for (int j = 0; j < 4; j++)
                acc[i][j] = __builtin_amdgcn_mfma_f32_16x16x32_bf16(a[i], b[j], acc[i][j], 0, 0, 0);
    }

#pragma unroll
    for (int i = 0; i < 4; i++) {
        int row = m0 + wm * 64 + i * 16 + fq * 4;
#pragma unroll
        for (int j = 0; j < 4; j++) {
            int col = n0 + wn * 64 + j * 16 + fr;
            float bv = bias ? bias[col] : 0.f;
#pragma unroll
            for (int r2 = 0; r2 < 4; r2++) {
                float v = acc[i][j][r2] + bv;
                if (OUT_BF16)
                    ((ushort_t*)Cout)[(size_t)(row + r2) * ldc + col] = f2bf(v);
                else
                    ((float*)Cout)[(size_t)(row + r2) * ldc + col] = v;
            }
        }
    }
}

// ---------------- gemm256: 256x256, BK=64, 8 waves, counted vmcnt, 3-bit XOR swizzle --
// out[32768][1024] = XC[32768][1088] @ WbigTX[1024][1088]^T + bias.
// Swizzle (T2, full G4 form): LDS[row][colb] = global[row][colb ^ ((row&7)<<4)].
// Stage side: row&7 = lane>>3, source col pre-XORed. Read side: row&7 = fr&7
// (A rows i*16+fr, B rows (wn&1)*64+fr — strides mult of 8). Residual 2-way = free.
// Schedule per K-tile t: [stage(t+1,Ah0); vmcnt(2); barrier; b-frags; 4x(quad+stage);
// barrier]. vmcnt(2): own 8 loads of tile t done, just-issued prefetch in flight.
#define NT 17   /* 1088 / 64 */
__global__ __launch_bounds__(512, 2) void gemm256(
    const ushort_t* __restrict__ A, const ushort_t* __restrict__ BT,
    float* __restrict__ out, const float* __restrict__ bias)
{
    extern __shared__ char smem[];     // 131072 B
    const int tid = threadIdx.x;
    const int w = tid >> 6, lane = tid & 63;
    const int wm = w >> 2, wn = w & 3;           // 2x4 waves -> 128x64 output each
    const int fr = lane & 15, fq = lane >> 4;

    // XCD swizzle: 512 wgs, 8 XCDs -> xcd gets 64 consecutive wgs (16 mtiles x 4 ntiles)
    int flat = blockIdx.x;
    int wg = (flat & 7) * 64 + (flat >> 3);
    const int m0 = (wg >> 2) * 256;
    const int n0 = (wg & 3) * 256;

    // ---- staging geometry (2 loads/thread per 16KB half-tile) ----
    const int w2 = w * 2;
    const int sr0 = (w2 + 0) * 8 + (lane >> 3);  // row in half, load 0
    const int sr1 = (w2 + 1) * 8 + (lane >> 3);  // row in half, load 1
    // pre-swizzled source col (elements): byte = ((lane&7)*16) ^ ((lane>>3)<<4)
    const int scole = ((((lane & 7) * 16) ^ ((lane >> 3) << 4)) >> 1);
    const size_t gA0 = (size_t)(m0 + sr0) * KX + scole;
    const size_t gA1 = (size_t)(m0 + sr1) * KX + scole;
    const size_t gB0 = (size_t)(n0 + sr0) * KX + scole;
    const size_t gB1 = (size_t)(n0 + sr1) * KX + scole;
    const int dstw = w2 * 1024;                  // wave-uniform byte base within half

    // ---- ds-read geometry: col byte = cb ^ ((fr&7)<<4) ----
    const int axor = (fr & 7) << 4;
    const int acol0 = (fq * 16) ^ axor;          // kk=0
    const int acol1 = (64 + fq * 16) ^ axor;     // kk=1
    const int aRd = wm * 16384 + fr * 128;                       // + buf*32768 + i*2048 + acol
    const int bRd = 65536 + (wn >> 1) * 16384 + ((wn & 1) * 64 + fr) * 128;

    floatx4 acc[8][4];
#pragma unroll
    for (int i = 0; i < 8; i++)
#pragma unroll
        for (int j = 0; j < 4; j++) acc[i][j] = (floatx4)0.f;

#define STAGE_A(buf, t, h)                                                   \
    do {                                                                     \
        char* d = smem + (buf) * 32768 + (h) * 16384 + dstw;                 \
        gload16(d,        A + gA0 + (size_t)(h) * 128 * KX + (t) * 64);      \
        gload16(d + 1024, A + gA1 + (size_t)(h) * 128 * KX + (t) * 64);     \
    } while (0)
#define STAGE_B(buf, t, h)                                                   \
    do {                                                                     \
        char* d = smem + 65536 + (buf) * 32768 + (h) * 16384 + dstw;         \
        gload16(d,        BT + gB0 + (size_t)(h) * 128 * KX + (t) * 64);     \
        gload16(d + 1024, BT + gB1 + (size_t)(h) * 128 * KX + (t) * 64);    \
    } while (0)

    // prologue: stage tile 0 into buf 0 (8 loads)
    STAGE_A(0, 0, 0); STAGE_A(0, 0, 1);
    STAGE_B(0, 0, 0); STAGE_B(0, 0, 1);

#pragma unroll 1
    for (int t = 0; t < NT; t++) {
        const int bufR = (t & 1) * 32768;
        const int bufW = ((t + 1) & 1) * 32768;
        const bool more = (t + 1 < NT);

        // ---- tile boundary: counted vmcnt + barrier ----
        if (more) {
            STAGE_A(bufW / 32768, t + 1, 0);
            __builtin_amdgcn_sched_barrier(0);
            asm volatile("s_waitcnt vmcnt(2)" ::: "memory");
        } else {
            __builtin_amdgcn_sched_barrier(0);
            asm volatile("s_waitcnt vmcnt(0)" ::: "memory");
        }
        __builtin_amdgcn_sched_barrier(0);
        __builtin_amdgcn_s_barrier();            // tile t fully visible in LDS
        __builtin_amdgcn_sched_barrier(0);

        // ---- b-fragments for the whole tile (8 x ds_read_b128) ----
        short8 b[4][2];
#pragma unroll
        for (int j = 0; j < 4; j++) {
            b[j][0] = *(const short8*)(smem + bufR + bRd + j * 2048 + acol0);
            b[j][1] = *(const short8*)(smem + bufR + bRd + j * 2048 + acol1);
        }

        // ---- 4 quadrants (i-pairs), staging interleaved ----
#pragma unroll
        for (int q = 0; q < 4; q++) {
            short8 a[2][2];
#pragma unroll
            for (int i2 = 0; i2 < 2; i2++) {
                int i = q * 2 + i2;
                a[i2][0] = *(const short8*)(smem + bufR + aRd + i * 2048 + acol0);
                a[i2][1] = *(const short8*)(smem + bufR + aRd + i * 2048 + acol1);
            }
            __builtin_amdgcn_s_setprio(1);
#pragma unroll
            for (int i2 = 0; i2 < 2; i2++)
#pragma unroll
                for (int j = 0; j < 4; j++)
#pragma unroll
                    for (int kk = 0; kk < 2; kk++)
                        acc[q * 2 + i2][j] = __builtin_amdgcn_mfma_f32_16x16x32_bf16(
                            a[i2][kk], b[j][kk], acc[q * 2 + i2][j], 0, 0, 0);
            __builtin_amdgcn_s_setprio(0);
            if (more) {
                if (q == 0) STAGE_A(bufW / 32768, t + 1, 1);
                else if (q == 1) STAGE_B(bufW / 32768, t + 1, 0);
                else if (q == 2) STAGE_B(bufW / 32768, t + 1, 1);
            }
        }

        __builtin_amdgcn_s_barrier();            // reads of buf[t] done before its restage
        __builtin_amdgcn_sched_barrier(0);
    }
#undef STAGE_A
#undef STAGE_B

    // ---- epilogue: C/D layout col=lane&15, row=(lane>>4)*4+reg ----
    float bv[4];
#pragma unroll
    for (int j = 0; j < 4; j++) bv[j] = bias[n0 + wn * 64 + j * 16 + fr];
#pragma unroll
    for (int i = 0; i < 8; i++) {
        int row = m0 + wm * 128 + i * 16 + fq * 4;
#pragma unroll
        for (int j = 0; j < 4; j++) {
            int col = n0 + wn * 64 + j * 16 + fr;
#pragma unroll
            for (int r2 = 0; r2 < 4; r2++)
                out[(size_t)(row + r2) * E_ + col] = acc[i][j][r2] + bv[j];
        }
    }
}

// ---------------- fused cvt + skinny GEMM1 (R8-proven; XC stride + zero-pad) --------
__global__ __launch_bounds__(256) void skinny16_cvt(
    const float* __restrict__ X,        // x [32768][1024] fp32
    const ushort_t* __restrict__ BT,    // BT16 [32][1024] (rows 16..31 zero)
    const float* __restrict__ bias,     // [32]
    ushort_t* __restrict__ XC)          // out: [32768][1088] = [bf16(x)|16 comb|48 zeros]
{
    const int tid = threadIdx.x, wave = tid >> 6, lane = tid & 63;
    const int m0 = blockIdx.x * 16;
    const int fr = lane & 15, fq = lane >> 4;
    const int k0w = wave * 256;

    floatx4 acc = (floatx4)0.f;
    const float*    px  = X  + (size_t)(m0 + fr) * E_ + k0w + fq * 8;
    ushort_t*       pxb = XC + (size_t)(m0 + fr) * KX + k0w + fq * 8;
    const ushort_t* pb  = BT + (size_t)fr * E_ + k0w + fq * 8;
#pragma unroll
    for (int kk = 0; kk < 256; kk += 32) {
        float4 v0 = *(const float4*)(px + kk);
        float4 v1 = *(const float4*)(px + kk + 4);
        short8 a;
        a[0] = (short)f2bf(v0.x); a[1] = (short)f2bf(v0.y);
        a[2] = (short)f2bf(v0.z); a[3] = (short)f2bf(v0.w);
        a[4] = (short)f2bf(v1.x); a[5] = (short)f2bf(v1.y);
        a[6] = (short)f2bf(v1.z); a[7] = (short)f2bf(v1.w);
        *(short8*)(pxb + kk) = a;
        short8 b0 = *(const short8*)(pb + kk);
        acc = __builtin_amdgcn_mfma_f32_16x16x32_bf16(a, b0, acc, 0, 0, 0);
    }

    __shared__ float red[4][16][16];
#pragma unroll
    for (int r = 0; r < 4; r++) red[wave][fq * 4 + r][fr] = acc[r];
    __syncthreads();
    const int row = tid >> 4, col = tid & 15;
    float v = red[0][row][col] + red[1][row][col] + red[2][row][col] + red[3][row][col]
            + bias[col];
    ushort_t* xr = XC + (size_t)(m0 + row) * KX;
    xr[1024 + col] = f2bf(v);
#pragma unroll
    for (int z = 0; z < 3; z++) xr[1040 + col + 16 * z] = (ushort_t)0;  // zero cols 1040..1087
}

// ---------------- fused scan (R8-proven; XC stride) ----------------
__global__ __launch_bounds__(256) void scan_fused(
    ushort_t* __restrict__ XC, float* __restrict__ final_state)
{
    const int b = blockIdx.x >> 3, d = blockIdx.x & 7;
    const int t = threadIdx.x;
    __shared__ float sA[256], sB[256];
    const size_t base = (size_t)b * S_ * KX;
    const int s0 = t * 16;

    float A = 1.f, Bv = 0.f;
    for (int s = s0; s < s0 + 16; s++) {
        size_t m = base + (size_t)s * KX;
        float z = bf2f(XC[m + 1032 + d]);
        float g = 1.f / (1.f + __expf(-z));
        float si = bf2f(XC[m + 1024 + d]);
        Bv = g * Bv + (1.f - g) * si;
        A *= g;
    }
    sA[t] = A; sB[t] = Bv;
    __syncthreads();

    float rA = A, rB = Bv;
    for (int off = 1; off < 256; off <<= 1) {
        float a = 1.f, b_ = 0.f;
        if (t >= off) { a = sA[t - off]; b_ = sB[t - off]; }
        __syncthreads();
        if (t >= off) {
            float nA = a * rA;
            float nB = rA * b_ + rB;
            rA = nA; rB = nB;
        }
        sA[t] = rA; sB[t] = rB;
        __syncthreads();
    }

    float state = (t == 0) ? 0.f : sB[t - 1];
    for (int s = s0; s < s0 + 16; s++) {
        size_t m = base + (size_t)s * KX;
        float z = bf2f(XC[m + 1032 + d]);
        float g = 1.f / (1.f + __expf(-z));
        float si = bf2f(XC[m + 1024 + d]);
        state = g * state + (1.f - g) * si;
        XC[m + 1024 + d] = f2bf(state);
    }
    if (t == 255) final_state[b * 8 + d] = state;
}

extern "C" void kernel_launch(void* const* d_in, const int* in_sizes, int n_in,
                              void* d_out, int out_size, void* d_ws, size_t ws_size,
                              hipStream_t stream)
{
    (void)in_sizes; (void)n_in; (void)out_size; (void)ws_size;
    const float* x     = (const float*)d_in[0];
    const float* W_in  = (const float*)d_in[1];
    const float* b_in  = (const float*)d_in[2];
    const float* W_g   = (const float*)d_in[3];
    const float* b_g   = (const float*)d_in[4];
    const float* W_out = (const float*)d_in[5];
    const float* b_out = (const float*)d_in[6];

    // workspace (~73.7 MB). Winb/WoutTa alias XC's head (dead before skinny overwrites).
    ushort_t* XC     = (ushort_t*)d_ws;                      // 32768*1088 bf16 = 71.3 MB
    ushort_t* Winb   = XC;                                   // 1024*1024 bf16 (aliased)
    ushort_t* WoutTa = XC + (size_t)E_ * E_;                 // 1024*1024 bf16 (aliased)
    ushort_t* WbigTX = XC + (size_t)M_TOTAL * KX;            // 1024*1088 bf16 = 2.23 MB
    ushort_t* WoutT2 = WbigTX + (size_t)E_ * KX;             // 1024*32 bf16 (legacy)
    ushort_t* BT16   = WoutT2 + (size_t)E_ * 32;             // 32*1024 bf16
    float*    Wc     = (float*)(BT16 + (size_t)32 * E_);     // 1024*8 fp32
    float*    bias16 = Wc + 1024 * 8;                        // 32
    float*    bias2v = bias16 + 32;                          // 1024

    float* outp = (float*)d_out;
    float* fs = outp + (size_t)M_TOTAL * E_;  // final_state at element 33554432

    // 1) elementwise weight prep (incl. WbigTX pad cols)
    prep_ew2<<<5376, 256, 0, stream>>>(W_in, W_out, Winb, WoutTa, WbigTX);
    // 2-4) R8-proven prep chain
    wcomb_kernel<<<E_, 64, 0, stream>>>(W_in, W_g, Wc);
    prep_small<<<256, 256, 0, stream>>>(W_in, Wc, W_out, b_in, W_g, b_g, BT16, WoutT2, bias16);
    bias2_kernel<<<E_ / 64, 64, 0, stream>>>(b_in, W_out, b_out, bias2v);

    // 5) WbigTX[:, :1024] = (W_in[:,:1024] @ W_out[:1024,:])^T   (ldc = 1088)
    gemm_bt<true><<<dim3(E_ / 128, E_ / 128), 256, 0, stream>>>(
        WoutTa, Winb, WbigTX, nullptr, E_, E_, E_, KX);

    // 6) fused cvt+skinny: XC = [bf16(x) | x@BT16^T + bias16 | zeros]
    skinny16_cvt<<<M_TOTAL / 16, 256, 0, stream>>>(x, BT16, bias16, XC);

    // 7) fused scan (overwrites state_in cols with states)
    scan_fused<<<64, 256, 0, stream>>>(XC, fs);

    // 8) gemm256: out = XC @ WbigTX^T + bias2  (K=1088, 128 KiB dynamic LDS)
    gemm256<<<512, 512, 131072, stream>>>(XC, WbigTX, outp, bias2v);
}